// Round 1
// baseline (612.755 us; speedup 1.0000x reference)
//
#include <hip/hip_runtime.h>
#include <hip/hip_bf16.h>
#include <math.h>

#define BB 32
#define SS 4096
#define HH 256

typedef __bf16 bf16x8 __attribute__((ext_vector_type(8)));
typedef float f32x4 __attribute__((ext_vector_type(4)));

#define GLOBAL_AS __attribute__((address_space(1)))
#define LDS_AS    __attribute__((address_space(3)))

__device__ inline bf16x8 cvt8(const float4& x, const float4& y) {
    union { __hip_bfloat162 p[4]; bf16x8 v; } u;
    u.p[0] = __float22bfloat162_rn(make_float2(x.x, x.y));
    u.p[1] = __float22bfloat162_rn(make_float2(x.z, x.w));
    u.p[2] = __float22bfloat162_rn(make_float2(y.x, y.y));
    u.p[3] = __float22bfloat162_rn(make_float2(y.z, y.w));
    return u.v;
}

// tanh(x) = 1 - 2/(e^{2x}+1). Clamp-free: exp2 overflow -> +inf -> rcp=0 -> 1;
// underflow -> 0 -> 1-2 = -1. ~5 VALU ops.
__device__ inline float fast_tanh(float x) {
    float e = __builtin_amdgcn_exp2f(x * 2.8853900817779268f);  // 2*log2(e)
    return 1.f - 2.f * __builtin_amdgcn_rcpf(e + 1.f);
}

// ---------------------------------------------------------------------------
// Prep (unchanged): blocks 0..255 swizzle W2 -> bf16 MFMA-B order;
// blocks 256..287: qq[b][h] = hidden[b]@W1[:,h] + W1_b[h] + W2_b[h];
// block 288: M = sum_h |V_w[h]|  (upper bound on V.tanh; V_b cancels).
// w2sw[((kc*16+nt)*64+lane)*8+j] = W2[kc*32+(lane>>4)*8+j][nt*16+(lane&15)]
// ---------------------------------------------------------------------------
__global__ void prep_kernel(const float* __restrict__ W2_w,
                            ushort* __restrict__ w2sw,
                            const float* __restrict__ hidden,
                            const float* __restrict__ W1_w,
                            const float* __restrict__ W1_b,
                            const float* __restrict__ W2_b,
                            const float* __restrict__ V_w,
                            float* __restrict__ qq,
                            float* __restrict__ Mout) {
    __shared__ float red[HH];
    const int t = threadIdx.x;
    if (blockIdx.x < 256) {
        const int i = blockIdx.x * 256 + t;
        const int j    = i & 7;
        const int lane = (i >> 3) & 63;
        const int nt   = (i >> 9) & 15;
        const int kc   = i >> 13;
        const int k = kc * 32 + ((lane >> 4) & 3) * 8 + j;
        const int n = nt * 16 + (lane & 15);
        __hip_bfloat16 h = __float2bfloat16(W2_w[k * HH + n]);
        w2sw[i] = *(ushort*)&h;
    } else if (blockIdx.x < 256 + BB) {
        const int b = blockIdx.x - 256;
        red[t] = hidden[b * HH + t];
        __syncthreads();
        float acc = 0.f;
#pragma unroll 16
        for (int k = 0; k < HH; ++k)
            acc = fmaf(red[k], W1_w[k * HH + t], acc);
        qq[b * HH + t] = acc + W1_b[t] + W2_b[t];
    } else {
        red[t] = fabsf(V_w[t]);
        __syncthreads();
        for (int off = 128; off > 0; off >>= 1) {
            if (t < off) red[t] += red[t + off];
            __syncthreads();
        }
        if (t == 0) Mout[0] = red[0];
    }
}

// ---------------------------------------------------------------------------
// Fused score + partial-context: grid (SS/512, BB), block 1024 = 16 waves,
// 1 block/CU (LDS-limited). W2 (128 KB bf16, swizzled) staged into LDS ONCE;
// each wave owns complete 16-row output strips (full n=256) -> the K-loop has
// NO barriers and NO vmcnt(0) drains: A streams global->reg with prefetch, B
// is read from resident LDS, scores reduce wave-locally via shfl_xor.
// 2 passes x 16 waves x 16 rows = 512 rows per block. Context partial kept in
// registers across passes; one LDS reduce at the end. 2 barriers per block.
// ---------------------------------------------------------------------------
__global__ __launch_bounds__(1024)
void score_ctx_kernel(const float* __restrict__ enc,
                      const ushort* __restrict__ w2sw,
                      const float* __restrict__ qq,
                      const float* __restrict__ V_w,
                      const float* __restrict__ Mptr,
                      float* __restrict__ wtilde,
                      float* __restrict__ part) {
    extern __shared__ char smem[];
    ushort* w2buf = (ushort*)smem;              // 131072 B: full swizzled W2
    float*  ctxl  = (float*)(smem + 131072);    // 16 KB: [16][256] ctx partials

    const int t    = threadIdx.x;
    const int b    = blockIdx.y;
    const int cx   = blockIdx.x;
    const int wid  = t >> 6;
    const int lane = t & 63;
    const int l15  = lane & 15;
    const int quad = lane >> 4;

    // Stage all of W2 into LDS (linear; 16 waves x 1KB per sweep, 8 sweeps).
    {
        const char* gsrc = (const char*)w2sw + t * 16;
        char* ldst = smem + wid * 1024;
#pragma unroll
        for (int i = 0; i < 8; ++i)
            __builtin_amdgcn_global_load_lds(
                (const GLOBAL_AS void*)(gsrc + i * 16384),
                (LDS_AS void*)(ldst + i * 16384), 16, 0, 0);
    }

    // Per-lane epilogue constants (L2-hot, once per block).
    float qv[16], vv[16];
#pragma unroll
    for (int nt = 0; nt < 16; ++nt) {
        qv[nt] = qq[b * HH + nt * 16 + l15];
        vv[nt] = V_w[nt * 16 + l15];
    }
    const float Mv = Mptr[0];
    float4 cacc = make_float4(0.f, 0.f, 0.f, 0.f);

    __syncthreads();   // W2 resident; no further barriers until ctx reduce

    for (int p = 0; p < 2; ++p) {
        const int s0 = cx * 512 + p * 256 + wid * 16;
        // A: row s0 + l15, k = kc*32 + quad*8 + j
        const float* rowp =
            enc + ((size_t)(b * SS + s0 + l15)) * HH + (quad << 3);

        f32x4 acc[16];
#pragma unroll
        for (int nt = 0; nt < 16; ++nt) acc[nt] = (f32x4)0.f;

        float4 a0x = *(const float4*)rowp;
        float4 a0y = *(const float4*)(rowp + 4);
#pragma unroll
        for (int kc = 0; kc < 8; ++kc) {
            float4 a1x, a1y;
            if (kc < 7) {   // issue next-kc prefetch before consuming current
                a1x = *(const float4*)(rowp + (kc + 1) * 32);
                a1y = *(const float4*)(rowp + (kc + 1) * 32 + 4);
            }
            const bf16x8 af = cvt8(a0x, a0y);
#pragma unroll
            for (int nt = 0; nt < 16; ++nt) {
                const bf16x8 bfr =
                    *(const bf16x8*)&w2buf[((kc * 16 + nt) * 64 + lane) * 8];
                acc[nt] = __builtin_amdgcn_mfma_f32_16x16x32_bf16(
                    af, bfr, acc[nt], 0, 0, 0);
            }
            if (kc < 7) { a0x = a1x; a0y = a1y; }
        }

        // Scores: C layout col = l15, local row = quad*4 + r.
        float p0[4] = {0.f, 0.f, 0.f, 0.f};
#pragma unroll
        for (int nt = 0; nt < 16; ++nt)
#pragma unroll
            for (int r = 0; r < 4; ++r)
                p0[r] = fmaf(vv[nt], fast_tanh(qv[nt] + acc[nt][r]), p0[r]);
        // reduce over the 16 columns held across l15 (stays inside quad group)
#pragma unroll
        for (int off = 1; off < 16; off <<= 1)
#pragma unroll
            for (int r = 0; r < 4; ++r)
                p0[r] += __shfl_xor(p0[r], off);

        float wv[4];
#pragma unroll
        for (int r = 0; r < 4; ++r) wv[r] = __expf(p0[r] - Mv);
        if (l15 == 0)
            *(float4*)&wtilde[(size_t)b * SS + s0 + quad * 4] =
                make_float4(wv[0], wv[1], wv[2], wv[3]);

        // Context partial over this wave's 16 rows (enc rows L1/L2-hot).
        const float* ep = enc + ((size_t)(b * SS + s0)) * HH + (lane << 2);
#pragma unroll
        for (int j = 0; j < 16; ++j) {
            const float wj = __shfl(wv[j & 3], (j >> 2) << 4);
            const float4 e = *(const float4*)(ep + (size_t)j * HH);
            cacc.x = fmaf(wj, e.x, cacc.x);
            cacc.y = fmaf(wj, e.y, cacc.y);
            cacc.z = fmaf(wj, e.z, cacc.z);
            cacc.w = fmaf(wj, e.w, cacc.w);
        }
    }

    // Block-level context reduce: 16 waves -> one partial per block.
    *(float4*)&ctxl[wid * HH + (lane << 2)] = cacc;
    __syncthreads();
    if (t < HH) {
        float s = 0.f;
#pragma unroll
        for (int w = 0; w < 16; ++w) s += ctxl[w * HH + t];
        part[((size_t)(b * 8 + cx)) * HH + t] = s;
    }
}

// ---------------------------------------------------------------------------
// Finish: grid (BB), block 256. l = sum_s wtilde; weights = wtilde/l;
// ctx = (sum_c part)/l.  (8 partials per b now.)
// ---------------------------------------------------------------------------
__global__ __launch_bounds__(256)
void finish_kernel(const float* __restrict__ wtilde,
                   const float* __restrict__ part,
                   float* __restrict__ weights_out,
                   float* __restrict__ ctx_out) {
    __shared__ float red[256];
    __shared__ float linv_s;
    const int b = blockIdx.x;
    const int t = threadIdx.x;

    const float4* wt4 = (const float4*)(wtilde + (size_t)b * SS);
    float4 vals[4];
    float l = 0.f;
#pragma unroll
    for (int i = 0; i < 4; ++i) {
        vals[i] = wt4[i * 256 + t];
        l += vals[i].x + vals[i].y + vals[i].z + vals[i].w;
    }
    red[t] = l;
    __syncthreads();
    for (int off = 128; off > 0; off >>= 1) {
        if (t < off) red[t] += red[t + off];
        __syncthreads();
    }
    if (t == 0) linv_s = 1.f / red[0];
    __syncthreads();
    const float linv = linv_s;

    float4* wo4 = (float4*)(weights_out + (size_t)b * SS);
#pragma unroll
    for (int i = 0; i < 4; ++i) {
        const float4 v = vals[i];
        wo4[i * 256 + t] =
            make_float4(v.x * linv, v.y * linv, v.z * linv, v.w * linv);
    }

    float a = 0.f;
#pragma unroll
    for (int c = 0; c < 8; ++c)
        a += part[((size_t)(b * 8 + c)) * HH + t];
    ctx_out[b * HH + t] = a * linv;
}

// ---------------------------------------------------------------------------
extern "C" void kernel_launch(void* const* d_in, const int* in_sizes, int n_in,
                              void* d_out, int out_size, void* d_ws, size_t ws_size,
                              hipStream_t stream) {
    const float* hidden = (const float*)d_in[0];
    const float* enc    = (const float*)d_in[1];
    const float* W1_w   = (const float*)d_in[2];
    const float* W1_b   = (const float*)d_in[3];
    const float* W2_w   = (const float*)d_in[4];
    const float* W2_b   = (const float*)d_in[5];
    const float* V_w    = (const float*)d_in[6];
    const float* V_b    = (const float*)d_in[7];
    (void)V_b;  // cancels in the shifted softmax

    float* out_weights = (float*)d_out;                 // B*S
    float* out_ctx     = (float*)d_out + BB * SS;       // B*H

    float* ws      = (float*)d_ws;
    float* ws_qq   = ws;                                 // 8192
    float* ws_wt   = ws_qq + BB * HH;                    // 131072
    float* ws_part = ws_wt + BB * SS;                    // (reserved as before)
    float* ws_M    = ws_part + BB * 64 * HH;             // 1
    ushort* ws_w2  = (ushort*)(ws_M + 4);                // 65536 bf16

    static bool attr_done = false;
    if (!attr_done) {
        hipFuncSetAttribute(reinterpret_cast<const void*>(score_ctx_kernel),
                            hipFuncAttributeMaxDynamicSharedMemorySize,
                            147456);
        attr_done = true;
    }

    prep_kernel<<<dim3(256 + BB + 1), dim3(256), 0, stream>>>(
        W2_w, ws_w2, hidden, W1_w, W1_b, W2_b, V_w, ws_qq, ws_M);
    score_ctx_kernel<<<dim3(SS / 512, BB), dim3(1024), 147456, stream>>>(
        enc, ws_w2, ws_qq, V_w, ws_M, ws_wt, ws_part);
    finish_kernel<<<dim3(BB), dim3(256), 0, stream>>>(
        ws_wt, ws_part, out_weights, out_ctx);
}

// Round 2
// 239.205 us; speedup vs baseline: 2.5616x; 2.5616x over previous
//
#include <hip/hip_runtime.h>
#include <hip/hip_bf16.h>
#include <math.h>

#define BB 32
#define SS 4096
#define HH 256

typedef __bf16 bf16x8 __attribute__((ext_vector_type(8)));
typedef float f32x4 __attribute__((ext_vector_type(4)));

#define GLOBAL_AS __attribute__((address_space(1)))
#define LDS_AS    __attribute__((address_space(3)))

__device__ inline bf16x8 cvt8(const float4& x, const float4& y) {
    union { __hip_bfloat162 p[4]; bf16x8 v; } u;
    u.p[0] = __float22bfloat162_rn(make_float2(x.x, x.y));
    u.p[1] = __float22bfloat162_rn(make_float2(x.z, x.w));
    u.p[2] = __float22bfloat162_rn(make_float2(y.x, y.y));
    u.p[3] = __float22bfloat162_rn(make_float2(y.z, y.w));
    return u.v;
}

// tanh(x) = 1 - 2/(e^{2x}+1). Clamp-free: exp2 overflow -> +inf -> rcp=0 -> 1;
// underflow -> 0 -> 1-2 = -1. ~5 VALU ops.
__device__ inline float fast_tanh(float x) {
    float e = __builtin_amdgcn_exp2f(x * 2.8853900817779268f);  // 2*log2(e)
    return 1.f - 2.f * __builtin_amdgcn_rcpf(e + 1.f);
}

// ---------------------------------------------------------------------------
// Prep (unchanged): blocks 0..255 swizzle W2 -> bf16 MFMA-B order;
// blocks 256..287: qq[b][h] = hidden[b]@W1[:,h] + W1_b[h] + W2_b[h];
// block 288: M = sum_h |V_w[h]|  (upper bound on V.tanh; V_b cancels).
// w2sw[((kc*16+nt)*64+lane)*8+j] = W2[kc*32+(lane>>4)*8+j][nt*16+(lane&15)]
// ---------------------------------------------------------------------------
__global__ void prep_kernel(const float* __restrict__ W2_w,
                            ushort* __restrict__ w2sw,
                            const float* __restrict__ hidden,
                            const float* __restrict__ W1_w,
                            const float* __restrict__ W1_b,
                            const float* __restrict__ W2_b,
                            const float* __restrict__ V_w,
                            float* __restrict__ qq,
                            float* __restrict__ Mout) {
    __shared__ float red[HH];
    const int t = threadIdx.x;
    if (blockIdx.x < 256) {
        const int i = blockIdx.x * 256 + t;
        const int j    = i & 7;
        const int lane = (i >> 3) & 63;
        const int nt   = (i >> 9) & 15;
        const int kc   = i >> 13;
        const int k = kc * 32 + ((lane >> 4) & 3) * 8 + j;
        const int n = nt * 16 + (lane & 15);
        __hip_bfloat16 h = __float2bfloat16(W2_w[k * HH + n]);
        w2sw[i] = *(ushort*)&h;
    } else if (blockIdx.x < 256 + BB) {
        const int b = blockIdx.x - 256;
        red[t] = hidden[b * HH + t];
        __syncthreads();
        float acc = 0.f;
#pragma unroll 16
        for (int k = 0; k < HH; ++k)
            acc = fmaf(red[k], W1_w[k * HH + t], acc);
        qq[b * HH + t] = acc + W1_b[t] + W2_b[t];
    } else {
        red[t] = fabsf(V_w[t]);
        __syncthreads();
        for (int off = 128; off > 0; off >>= 1) {
            if (t < off) red[t] += red[t + off];
            __syncthreads();
        }
        if (t == 0) Mout[0] = red[0];
    }
}

// ---------------------------------------------------------------------------
// Fused score + partial-context: grid (SS/512, BB), block 1024 = 16 waves
// (8 m-strips x 2 n-halves), 1 block/CU (LDS-limited; __launch_bounds__
// (1024,4) pins the VGPR cap at 128 -> no spills, unlike round 1's 64-cap).
// W2 (128 KB bf16, swizzled) staged into LDS ONCE. K-loop barrier-free:
// A streams global->reg with 1-deep prefetch, B from resident LDS,
// acc[8] = 32 VGPRs/wave. Per pass (128 rows): ONE barrier for the 2-way
// n-half score combine via double-buffered sc LDS (parity covers WAR across
// passes). Ctx partial lives in registers across all 4 passes.
// ---------------------------------------------------------------------------
__global__ __launch_bounds__(1024, 4)
void score_ctx_kernel(const float* __restrict__ enc,
                      const ushort* __restrict__ w2sw,
                      const float* __restrict__ qq,
                      const float* __restrict__ V_w,
                      const float* __restrict__ Mptr,
                      float* __restrict__ wtilde,
                      float* __restrict__ part) {
    extern __shared__ char smem[];
    ushort* w2buf = (ushort*)smem;               // 131072 B: full swizzled W2
    float*  sc    = (float*)(smem + 131072);     // [2][2][128] = 2048 B
    float*  ctxl  = (float*)(smem + 133120);     // [16][256] = 16384 B

    const int t    = threadIdx.x;
    const int b    = blockIdx.y;
    const int cx   = blockIdx.x;
    const int wid  = t >> 6;
    const int lane = t & 63;
    const int l15  = lane & 15;
    const int quad = lane >> 4;
    const int mw   = wid & 7;
    const int nw   = wid >> 3;

    // Stage all of W2 into LDS (linear; 16 waves x 1KB per sweep, 8 sweeps).
    {
        const char* gsrc = (const char*)w2sw + t * 16;
        char* ldst = smem + wid * 1024;
#pragma unroll
        for (int i = 0; i < 8; ++i)
            __builtin_amdgcn_global_load_lds(
                (const GLOBAL_AS void*)(gsrc + i * 16384),
                (LDS_AS void*)(ldst + i * 16384), 16, 0, 0);
    }

    const float Mv = Mptr[0];
    float4 cacc = make_float4(0.f, 0.f, 0.f, 0.f);

    __syncthreads();   // W2 resident

    for (int p = 0; p < 4; ++p) {
        const int par  = p & 1;
        const int srow = cx * 512 + p * 128 + mw * 16;   // this wave's strip
        // A: row srow + l15, k = kc*32 + quad*8 + j
        const float* rowp =
            enc + ((size_t)(b * SS + srow + l15)) * HH + (quad << 3);

        f32x4 acc[8];
#pragma unroll
        for (int nt = 0; nt < 8; ++nt) acc[nt] = (f32x4)0.f;

        float4 a0x = *(const float4*)rowp;
        float4 a0y = *(const float4*)(rowp + 4);
#pragma unroll
        for (int kc = 0; kc < 8; ++kc) {
            float4 a1x, a1y;
            if (kc < 7) {   // issue next-kc prefetch before consuming current
                a1x = *(const float4*)(rowp + (kc + 1) * 32);
                a1y = *(const float4*)(rowp + (kc + 1) * 32 + 4);
            }
            const bf16x8 af = cvt8(a0x, a0y);
#pragma unroll
            for (int nt = 0; nt < 8; ++nt) {
                const bf16x8 bfr = *(const bf16x8*)
                    &w2buf[((kc * 16 + nw * 8 + nt) * 64 + lane) * 8];
                acc[nt] = __builtin_amdgcn_mfma_f32_16x16x32_bf16(
                    af, bfr, acc[nt], 0, 0, 0);
            }
            if (kc < 7) { a0x = a1x; a0y = a1y; }
        }

        // Scores over this wave's n-half. C layout: col=l15, row=quad*4+r.
        float p0[4] = {0.f, 0.f, 0.f, 0.f};
#pragma unroll
        for (int nt = 0; nt < 8; ++nt) {
            const int n = nw * 128 + nt * 16 + l15;
            const float qn = qq[b * HH + n];   // L1-hot after pass 0
            const float vn = V_w[n];
#pragma unroll
            for (int r = 0; r < 4; ++r)
                p0[r] = fmaf(vn, fast_tanh(qn + acc[nt][r]), p0[r]);
        }
#pragma unroll
        for (int off = 1; off < 16; off <<= 1)
#pragma unroll
            for (int r = 0; r < 4; ++r)
                p0[r] += __shfl_xor(p0[r], off);

        if (l15 == 0)
            *(float4*)&sc[(par * 2 + nw) * 128 + mw * 16 + quad * 4] =
                make_float4(p0[0], p0[1], p0[2], p0[3]);
        __syncthreads();

        if (nw == 0 && l15 == 0) {
            const float* o = &sc[(par * 2 + 1) * 128 + mw * 16 + quad * 4];
            *(float4*)&wtilde[(size_t)b * SS + srow + quad * 4] =
                make_float4(__expf(p0[0] + o[0] - Mv),
                            __expf(p0[1] + o[1] - Mv),
                            __expf(p0[2] + o[2] - Mv),
                            __expf(p0[3] + o[3] - Mv));
        }

        // Ctx partial over this wave's 8 rows (enc rows L1/L2-hot).
        const float* ep =
            enc + ((size_t)(b * SS + srow + nw * 8)) * HH + (lane << 2);
        const float* s0p = &sc[(par * 2 + 0) * 128 + mw * 16 + nw * 8];
        const float* s1p = &sc[(par * 2 + 1) * 128 + mw * 16 + nw * 8];
#pragma unroll
        for (int jj = 0; jj < 8; ++jj) {
            const float w = __expf(s0p[jj] + s1p[jj] - Mv);  // LDS broadcast
            const float4 e = *(const float4*)(ep + (size_t)jj * HH);
            cacc.x = fmaf(w, e.x, cacc.x);
            cacc.y = fmaf(w, e.y, cacc.y);
            cacc.z = fmaf(w, e.z, cacc.z);
            cacc.w = fmaf(w, e.w, cacc.w);
        }
    }

    // Block-level context reduce: 16 waves -> one partial per block.
    *(float4*)&ctxl[wid * HH + (lane << 2)] = cacc;
    __syncthreads();
    if (t < HH) {
        float s = 0.f;
#pragma unroll
        for (int w = 0; w < 16; ++w) s += ctxl[w * HH + t];
        part[((size_t)(b * 8 + cx)) * HH + t] = s;
    }
}

// ---------------------------------------------------------------------------
// Finish: grid (BB), block 256. l = sum_s wtilde; weights = wtilde/l;
// ctx = (sum_c part)/l.  (8 partials per b.)
// ---------------------------------------------------------------------------
__global__ __launch_bounds__(256)
void finish_kernel(const float* __restrict__ wtilde,
                   const float* __restrict__ part,
                   float* __restrict__ weights_out,
                   float* __restrict__ ctx_out) {
    __shared__ float red[256];
    __shared__ float linv_s;
    const int b = blockIdx.x;
    const int t = threadIdx.x;

    const float4* wt4 = (const float4*)(wtilde + (size_t)b * SS);
    float4 vals[4];
    float l = 0.f;
#pragma unroll
    for (int i = 0; i < 4; ++i) {
        vals[i] = wt4[i * 256 + t];
        l += vals[i].x + vals[i].y + vals[i].z + vals[i].w;
    }
    red[t] = l;
    __syncthreads();
    for (int off = 128; off > 0; off >>= 1) {
        if (t < off) red[t] += red[t + off];
        __syncthreads();
    }
    if (t == 0) linv_s = 1.f / red[0];
    __syncthreads();
    const float linv = linv_s;

    float4* wo4 = (float4*)(weights_out + (size_t)b * SS);
#pragma unroll
    for (int i = 0; i < 4; ++i) {
        const float4 v = vals[i];
        wo4[i * 256 + t] =
            make_float4(v.x * linv, v.y * linv, v.z * linv, v.w * linv);
    }

    float a = 0.f;
#pragma unroll
    for (int c = 0; c < 8; ++c)
        a += part[((size_t)(b * 8 + c)) * HH + t];
    ctx_out[b * HH + t] = a * linv;
}

// ---------------------------------------------------------------------------
extern "C" void kernel_launch(void* const* d_in, const int* in_sizes, int n_in,
                              void* d_out, int out_size, void* d_ws, size_t ws_size,
                              hipStream_t stream) {
    const float* hidden = (const float*)d_in[0];
    const float* enc    = (const float*)d_in[1];
    const float* W1_w   = (const float*)d_in[2];
    const float* W1_b   = (const float*)d_in[3];
    const float* W2_w   = (const float*)d_in[4];
    const float* W2_b   = (const float*)d_in[5];
    const float* V_w    = (const float*)d_in[6];
    const float* V_b    = (const float*)d_in[7];
    (void)V_b;  // cancels in the shifted softmax

    float* out_weights = (float*)d_out;                 // B*S
    float* out_ctx     = (float*)d_out + BB * SS;       // B*H

    float* ws      = (float*)d_ws;
    float* ws_qq   = ws;                                 // 8192
    float* ws_wt   = ws_qq + BB * HH;                    // 131072
    float* ws_part = ws_wt + BB * SS;                    // (region reserved)
    float* ws_M    = ws_part + BB * 64 * HH;             // 1
    ushort* ws_w2  = (ushort*)(ws_M + 4);                // 65536 bf16

    static bool attr_done = false;
    if (!attr_done) {
        hipFuncSetAttribute(reinterpret_cast<const void*>(score_ctx_kernel),
                            hipFuncAttributeMaxDynamicSharedMemorySize,
                            149504);
        attr_done = true;
    }

    prep_kernel<<<dim3(256 + BB + 1), dim3(256), 0, stream>>>(
        W2_w, ws_w2, hidden, W1_w, W1_b, W2_b, V_w, ws_qq, ws_M);
    score_ctx_kernel<<<dim3(SS / 512, BB), dim3(1024), 149504, stream>>>(
        enc, ws_w2, ws_qq, V_w, ws_M, ws_wt, ws_part);
    finish_kernel<<<dim3(BB), dim3(256), 0, stream>>>(
        ws_wt, ws_part, out_weights, out_ctx);
}